// Round 2
// baseline (218.028 us; speedup 1.0000x reference)
//
#include <hip/hip_runtime.h>
#include <hip/hip_bf16.h>

#define NROW 8192
#define CDIM 128
#define NCLS 10
// 1/(T*ln2) = 10*log2(e)
#define EXP2_SCALE 14.4269504088896f

typedef _Float16 f16x8 __attribute__((ext_vector_type(8)));
typedef _Float16 f16x2 __attribute__((ext_vector_type(2)));
typedef float f32x4 __attribute__((ext_vector_type(4)));

typedef __attribute__((address_space(1))) const unsigned int gu32;
typedef __attribute__((address_space(3))) unsigned int lu32;

__device__ __forceinline__ void gload_lds16(const _Float16* g, _Float16* l) {
  __builtin_amdgcn_global_load_lds((gu32*)g, (lu32*)l, 16, 0, 0);
}

// ---------------- normalize: x -> xn (f32), xnh (f16) -------------------
__global__ void normalize_kernel(const float* __restrict__ x,
                                 float* __restrict__ xn,
                                 _Float16* __restrict__ xnh) {
  const int w = threadIdx.x >> 6, l = threadIdx.x & 63;
  const int row = blockIdx.x * 4 + w;
  const float2 v = *(const float2*)&x[row * CDIM + l * 2];
  float ss = v.x * v.x + v.y * v.y;
#pragma unroll
  for (int off = 32; off; off >>= 1) ss += __shfl_xor(ss, off);
  const float nrm = fmaxf(sqrtf(ss), 1e-12f);
  const float a = v.x / nrm, b = v.y / nrm;
  ((float2*)xn)[row * 64 + l] = make_float2(a, b);
  f16x2 h;
  h[0] = (_Float16)a;
  h[1] = (_Float16)b;
  ((f16x2*)xnh)[row * 64 + l] = h;
}

// ---------------- class histogram --------------------------------------
__global__ void hist_kernel(const int* __restrict__ y, int* __restrict__ hist) {
  __shared__ int h[16];
  if (threadIdx.x < 16) h[threadIdx.x] = 0;
  __syncthreads();
  for (int i = blockIdx.x * 256 + threadIdx.x; i < NROW; i += 256 * 16)
    atomicAdd(&h[y[i]], 1);
  __syncthreads();
  if (threadIdx.x < NCLS) atomicAdd(&hist[threadIdx.x], h[threadIdx.x]);
}

// ---------------- per-class sums of normalized rows ---------------------
__global__ void csum_kernel(const float* __restrict__ xn,
                            const int* __restrict__ y,
                            float* __restrict__ S) {
  __shared__ float s[NCLS * CDIM];
  for (int i = threadIdx.x; i < NCLS * CDIM; i += 256) s[i] = 0.f;
  __syncthreads();
  const int f = threadIdx.x & 127;
  const int rs = threadIdx.x >> 7;  // 0/1
  const int base = blockIdx.x * 512;
  for (int r = rs; r < 512; r += 2) {
    const int row = base + r;
    const int c = y[row];
    atomicAdd(&s[c * CDIM + f], xn[row * CDIM + f]);
  }
  __syncthreads();
  for (int i = threadIdx.x; i < NCLS * CDIM; i += 256) atomicAdd(&S[i], s[i]);
}

// ---------------- Gram GEMM + exp + row-sum epilogue --------------------
// 128x128 tile per block, 4 waves 2x2, wave tile 64x64 (4x4 frags 16x16x32).
// LDS layout: row-major [128][128] f16, 16B chunks XOR-swizzled:
//   LDS[r][cpos] holds data chunk (cpos ^ (r&7))  (linear dest for
//   global_load_lds; swizzle realized by pre-swizzling the GLOBAL source).
__global__ __launch_bounds__(256, 2) void gemm_exp_kernel(
    const _Float16* __restrict__ xnh, float* __restrict__ partial) {
  __shared__ _Float16 As[128 * 128];
  __shared__ _Float16 Bs[128 * 128];
  __shared__ float row_lds[128];

  const int tid = threadIdx.x;
  const int l = tid & 63, w = tid >> 6;
  const int lane16 = l & 15, lanehi = l >> 4;
  const int bi = blockIdx.y, bj = blockIdx.x;

  if (tid < 128) row_lds[tid] = 0.f;

  const int rowA0 = bi * 128;
  const int rowB0 = bj * 128;
#pragma unroll
  for (int i = 0; i < 8; ++i) {
    const int rg = w * 32 + i * 4;        // first row of this 1KB chunk
    const int rl = rg + lanehi;           // row this lane fetches
    const int csrc = lane16 ^ (rl & 7);   // pre-swizzled source chunk
    gload_lds16(&xnh[(rowA0 + rl) * CDIM + csrc * 8], &As[rg * 128]);
    gload_lds16(&xnh[(rowB0 + rl) * CDIM + csrc * 8], &Bs[rg * 128]);
  }
  __syncthreads();

  const int wr = w >> 1, wc = w & 1;
  f32x4 acc[4][4];
#pragma unroll
  for (int fm = 0; fm < 4; ++fm)
#pragma unroll
    for (int fn = 0; fn < 4; ++fn) acc[fm][fn] = (f32x4){0.f, 0.f, 0.f, 0.f};

#pragma unroll
  for (int kk = 0; kk < 4; ++kk) {
    f16x8 a[4], b[4];
#pragma unroll
    for (int f = 0; f < 4; ++f) {
      const int ra = wr * 64 + f * 16 + lane16;
      const int ca = (kk * 4 + lanehi) ^ (ra & 7);
      a[f] = *(const f16x8*)&As[ra * 128 + ca * 8];
      const int rb = wc * 64 + f * 16 + lane16;
      const int cb = (kk * 4 + lanehi) ^ (rb & 7);
      b[f] = *(const f16x8*)&Bs[rb * 128 + cb * 8];
    }
#pragma unroll
    for (int fm = 0; fm < 4; ++fm)
#pragma unroll
      for (int fn = 0; fn < 4; ++fn)
        acc[fm][fn] = __builtin_amdgcn_mfma_f32_16x16x32_f16(
            a[fm], b[fn], acc[fm][fn], 0, 0, 0);
  }

  // epilogue: p = sum_j exp(s/T) over this wave's 64 cols, skip diagonal
  const int growb = bi * 128 + wr * 64;
  const int gcolb = bj * 128 + wc * 64;
#pragma unroll
  for (int fm = 0; fm < 4; ++fm) {
#pragma unroll
    for (int e = 0; e < 4; ++e) {
      const int row = growb + fm * 16 + lanehi * 4 + e;
      float p = 0.f;
#pragma unroll
      for (int fn = 0; fn < 4; ++fn) {
        const int col = gcolb + fn * 16 + lane16;
        const float v = exp2f(acc[fm][fn][e] * EXP2_SCALE);
        p += (col != row) ? v : 0.f;
      }
#pragma unroll
      for (int off = 1; off < 16; off <<= 1) p += __shfl_xor(p, off);
      if (lane16 == 0)
        atomicAdd(&row_lds[wr * 64 + fm * 16 + lanehi * 4 + e], p);
    }
  }
  __syncthreads();
  if (tid < 128) partial[(long)bj * NROW + bi * 128 + tid] = row_lds[tid];
}

// ---------------- final per-row loss + global reduce --------------------
__global__ void final_kernel(const float* __restrict__ xn,
                             const int* __restrict__ y,
                             const float* __restrict__ S,
                             const int* __restrict__ hist,
                             const float* __restrict__ partial,
                             float* __restrict__ out) {
  const int l = threadIdx.x & 63, w = threadIdx.x >> 6;
  const int waveid = blockIdx.x * 4 + w;  // 0..511
  float accum = 0.f;
  for (int t = 0; t < 16; ++t) {
    const int row = waveid + 512 * t;
    float d = partial[(long)l * NROW + row];  // 64 column-block partials
    const int c = y[row];
    const float2 xv = *(const float2*)&xn[row * CDIM + l * 2];
    const float2 sv = *(const float2*)&S[c * CDIM + l * 2];
    float dot = xv.x * sv.x + xv.y * sv.y;
    float sf = xv.x * xv.x + xv.y * xv.y;
#pragma unroll
    for (int off = 32; off; off >>= 1) {
      d += __shfl_xor(d, off);
      dot += __shfl_xor(dot, off);
      sf += __shfl_xor(sf, off);
    }
    const int cnt = hist[c] - 1;
    float row_val = 0.f;
    if (cnt > 0) {
      const float possum = dot - sf;  // exclude self term
      row_val = -(possum * 10.0f - (float)cnt * logf(d)) / (float)cnt;
    }
    accum += row_val;
  }
  __shared__ float bsum[4];
  if (l == 0) bsum[w] = accum;
  __syncthreads();
  if (threadIdx.x == 0)
    atomicAdd(out, bsum[0] + bsum[1] + bsum[2] + bsum[3]);
}

extern "C" void kernel_launch(void* const* d_in, const int* in_sizes, int n_in,
                              void* d_out, int out_size, void* d_ws,
                              size_t ws_size, hipStream_t stream) {
  const float* x = (const float*)d_in[0];
  const int* y = (const int*)d_in[1];
  float* out = (float*)d_out;
  char* ws = (char*)d_ws;

  float* xn = (float*)(ws);                    // 4 MB  fp32 normalized
  _Float16* xnh = (_Float16*)(ws + (4 << 20)); // 2 MB  f16 normalized
  float* partial = (float*)(ws + (6 << 20));   // 2 MB  [64 col-blocks][8192]
  float* S = (float*)(ws + (8 << 20));         // 5 KB  class sums
  int* hist = (int*)(ws + (8 << 20) + 8192);   // 40 B  class histogram

  hipMemsetAsync(S, 0, NCLS * CDIM * sizeof(float), stream);
  hipMemsetAsync(hist, 0, 64, stream);
  hipMemsetAsync(out, 0, sizeof(float), stream);

  normalize_kernel<<<NROW / 4, 256, 0, stream>>>(x, xn, xnh);
  hist_kernel<<<16, 256, 0, stream>>>(y, hist);
  csum_kernel<<<16, 256, 0, stream>>>(xn, y, S);
  gemm_exp_kernel<<<dim3(64, 64), 256, 0, stream>>>(xnh, partial);
  final_kernel<<<128, 256, 0, stream>>>(xn, y, S, hist, partial, out);
}

// Round 3
// 132.948 us; speedup vs baseline: 1.6400x; 1.6400x over previous
//
#include <hip/hip_runtime.h>
#include <hip/hip_bf16.h>

#define NROW 8192
#define CDIM 128
#define NCLS 10
// 1/(T*ln2) = 10*log2(e)
#define EXP2_SCALE 14.4269504088896f

typedef _Float16 f16x8 __attribute__((ext_vector_type(8)));
typedef _Float16 f16x2 __attribute__((ext_vector_type(2)));
typedef float f32x4 __attribute__((ext_vector_type(4)));

typedef __attribute__((address_space(1))) const unsigned int gu32;
typedef __attribute__((address_space(3))) unsigned int lu32;

__device__ __forceinline__ void gload_lds16(const _Float16* g, _Float16* l) {
  __builtin_amdgcn_global_load_lds((gu32*)g, (lu32*)l, 16, 0, 0);
}

// ---------------- normalize: x -> xn (f32), xnh (f16) -------------------
__global__ void normalize_kernel(const float* __restrict__ x,
                                 float* __restrict__ xn,
                                 _Float16* __restrict__ xnh) {
  const int w = threadIdx.x >> 6, l = threadIdx.x & 63;
  const int row = blockIdx.x * 4 + w;
  const float2 v = *(const float2*)&x[row * CDIM + l * 2];
  float ss = v.x * v.x + v.y * v.y;
#pragma unroll
  for (int off = 32; off; off >>= 1) ss += __shfl_xor(ss, off);
  const float nrm = fmaxf(sqrtf(ss), 1e-12f);
  const float a = v.x / nrm, b = v.y / nrm;
  ((float2*)xn)[row * 64 + l] = make_float2(a, b);
  f16x2 h;
  h[0] = (_Float16)a;
  h[1] = (_Float16)b;
  ((f16x2*)xnh)[row * 64 + l] = h;
}

// ---------------- class histogram --------------------------------------
__global__ void hist_kernel(const int* __restrict__ y, int* __restrict__ hist) {
  __shared__ int h[16];
  if (threadIdx.x < 16) h[threadIdx.x] = 0;
  __syncthreads();
  for (int i = blockIdx.x * 256 + threadIdx.x; i < NROW; i += 256 * 16)
    atomicAdd(&h[y[i]], 1);
  __syncthreads();
  if (threadIdx.x < NCLS) atomicAdd(&hist[threadIdx.x], h[threadIdx.x]);
}

// ---------------- per-class sums, stage 1: 256 blocks x 32 rows ---------
// Per-thread register prefetch of 16 rows breaks the latency chain; LDS
// accumulator s[half][class][feat] has a single writer per address
// (wave = one row at a time, lanes = consecutive feats -> conflict-free).
__global__ __launch_bounds__(256) void csum1_kernel(
    const float* __restrict__ xn, const int* __restrict__ y,
    float* __restrict__ pS) {
  __shared__ float s[2][NCLS][CDIM];
  const int t = threadIdx.x;
  const int f = t & 127, h = t >> 7;
  for (int i = t; i < 2 * NCLS * CDIM; i += 256) ((float*)s)[i] = 0.f;
  __syncthreads();
  const int row0 = blockIdx.x * 32 + h * 16;
  float v[16];
  int c[16];
#pragma unroll
  for (int r = 0; r < 16; ++r) {
    v[r] = xn[(row0 + r) * CDIM + f];
    c[r] = y[row0 + r];
  }
#pragma unroll
  for (int r = 0; r < 16; ++r) s[h][c[r]][f] += v[r];
  __syncthreads();
  for (int i = t; i < NCLS * CDIM; i += 256)
    pS[blockIdx.x * (NCLS * CDIM) + i] = ((float*)s[0])[i] + ((float*)s[1])[i];
}

// ---------------- per-class sums, stage 2: wave per (c,f) ---------------
__global__ void csum2_kernel(const float* __restrict__ pS,
                             float* __restrict__ S) {
  const int w = threadIdx.x >> 6, l = threadIdx.x & 63;
  const int i = blockIdx.x * 4 + w;  // 0..1279
  float a = 0.f;
#pragma unroll
  for (int k = 0; k < 4; ++k) a += pS[(l * 4 + k) * (NCLS * CDIM) + i];
#pragma unroll
  for (int off = 32; off; off >>= 1) a += __shfl_xor(a, off);
  if (l == 0) S[i] = a;
}

// ---------------- Gram GEMM + exp + row-sum epilogue --------------------
// Symmetric: only tiles bj >= bi run. Off-diagonal tiles emit BOTH the
// row-sums (rows of bi-block, slot bj) and the column-sums (rows of
// bj-block, slot bi) since s_ji == s_ij. partial layout [8192][64] so the
// final kernel reads coalesced. LDS 16B chunks XOR-swizzled via
// pre-swizzled GLOBAL source (linear dest for global_load_lds).
__global__ __launch_bounds__(256, 2) void gemm_exp_kernel(
    const _Float16* __restrict__ xnh, float* __restrict__ partial) {
  __shared__ _Float16 As[128 * 128];
  __shared__ _Float16 Bs[128 * 128];
  __shared__ float row_lds[128];
  __shared__ float col_lds[128];

  const int bi = blockIdx.y, bj = blockIdx.x;
  if (bj < bi) return;
  const bool diag = (bi == bj);

  const int tid = threadIdx.x;
  const int l = tid & 63, w = tid >> 6;
  const int lane16 = l & 15, lanehi = l >> 4;

  if (tid < 128) {
    row_lds[tid] = 0.f;
    col_lds[tid] = 0.f;
  }

  const int rowA0 = bi * 128;
  const int rowB0 = bj * 128;
#pragma unroll
  for (int i = 0; i < 8; ++i) {
    const int rg = w * 32 + i * 4;       // first row of this 1KB chunk
    const int rl = rg + lanehi;          // row this lane fetches
    const int csrc = lane16 ^ (rl & 7);  // pre-swizzled source chunk
    gload_lds16(&xnh[(rowA0 + rl) * CDIM + csrc * 8], &As[rg * 128]);
    gload_lds16(&xnh[(rowB0 + rl) * CDIM + csrc * 8], &Bs[rg * 128]);
  }
  __syncthreads();

  const int wr = w >> 1, wc = w & 1;
  f32x4 acc[4][4];
#pragma unroll
  for (int fm = 0; fm < 4; ++fm)
#pragma unroll
    for (int fn = 0; fn < 4; ++fn) acc[fm][fn] = (f32x4){0.f, 0.f, 0.f, 0.f};

#pragma unroll
  for (int kk = 0; kk < 4; ++kk) {
    f16x8 a[4], b[4];
#pragma unroll
    for (int f = 0; f < 4; ++f) {
      const int ra = wr * 64 + f * 16 + lane16;
      const int ca = (kk * 4 + lanehi) ^ (ra & 7);
      a[f] = *(const f16x8*)&As[ra * 128 + ca * 8];
      const int rb = wc * 64 + f * 16 + lane16;
      const int cb = (kk * 4 + lanehi) ^ (rb & 7);
      b[f] = *(const f16x8*)&Bs[rb * 128 + cb * 8];
    }
#pragma unroll
    for (int fm = 0; fm < 4; ++fm)
#pragma unroll
      for (int fn = 0; fn < 4; ++fn)
        acc[fm][fn] = __builtin_amdgcn_mfma_f32_16x16x32_f16(
            a[fm], b[fn], acc[fm][fn], 0, 0, 0);
  }

  // epilogue: exp2(s*scale); row partials pr[fm][e]; col sums per fn.
  const int growb = bi * 128 + wr * 64;
  const int gcolb = bj * 128 + wc * 64;
  float pr[4][4];
#pragma unroll
  for (int fm = 0; fm < 4; ++fm)
#pragma unroll
    for (int e = 0; e < 4; ++e) pr[fm][e] = 0.f;

#pragma unroll
  for (int fn = 0; fn < 4; ++fn) {
    float q = 0.f;
    const int col = gcolb + fn * 16 + lane16;
#pragma unroll
    for (int fm = 0; fm < 4; ++fm) {
#pragma unroll
      for (int e = 0; e < 4; ++e) {
        float v = exp2f(acc[fm][fn][e] * EXP2_SCALE);
        const int row = growb + fm * 16 + lanehi * 4 + e;
        if (diag && row == col) v = 0.f;
        pr[fm][e] += v;
        q += v;
      }
    }
    if (!diag) {
      q += __shfl_xor(q, 16);
      q += __shfl_xor(q, 32);
      if (l < 16) atomicAdd(&col_lds[wc * 64 + fn * 16 + l], q);
    }
  }
#pragma unroll
  for (int fm = 0; fm < 4; ++fm)
#pragma unroll
    for (int e = 0; e < 4; ++e) {
      float p = pr[fm][e];
      p += __shfl_xor(p, 1);
      p += __shfl_xor(p, 2);
      p += __shfl_xor(p, 4);
      p += __shfl_xor(p, 8);
      if (lane16 == 0)
        atomicAdd(&row_lds[wr * 64 + fm * 16 + lanehi * 4 + e], p);
    }
  __syncthreads();
  if (tid < 128) {
    partial[(long)(bi * 128 + tid) * 64 + bj] = row_lds[tid];
    if (!diag) partial[(long)(bj * 128 + tid) * 64 + bi] = col_lds[tid];
  }
}

// ---------------- final per-row loss + global reduce --------------------
__global__ void final_kernel(const float* __restrict__ xn,
                             const int* __restrict__ y,
                             const float* __restrict__ S,
                             const int* __restrict__ hist,
                             const float* __restrict__ partial,
                             float* __restrict__ out) {
  const int l = threadIdx.x & 63, w = threadIdx.x >> 6;
  const int waveid = blockIdx.x * 4 + w;  // 0..511
  float accum = 0.f;
  for (int t = 0; t < 16; ++t) {
    const int row = waveid + 512 * t;
    float d = partial[(long)row * 64 + l];  // coalesced: 64 col-block sums
    const int c = y[row];
    const float2 xv = *(const float2*)&xn[row * CDIM + l * 2];
    const float2 sv = *(const float2*)&S[c * CDIM + l * 2];
    float dot = xv.x * sv.x + xv.y * sv.y;
    float sf = xv.x * xv.x + xv.y * xv.y;
#pragma unroll
    for (int off = 32; off; off >>= 1) {
      d += __shfl_xor(d, off);
      dot += __shfl_xor(dot, off);
      sf += __shfl_xor(sf, off);
    }
    const int cnt = hist[c] - 1;
    float row_val = 0.f;
    if (cnt > 0) {
      const float possum = dot - sf;  // exclude self term
      row_val = -(possum * 10.0f - (float)cnt * logf(d)) / (float)cnt;
    }
    accum += row_val;
  }
  __shared__ float bsum[4];
  if (l == 0) bsum[w] = accum;
  __syncthreads();
  if (threadIdx.x == 0)
    atomicAdd(out, bsum[0] + bsum[1] + bsum[2] + bsum[3]);
}

extern "C" void kernel_launch(void* const* d_in, const int* in_sizes, int n_in,
                              void* d_out, int out_size, void* d_ws,
                              size_t ws_size, hipStream_t stream) {
  const float* x = (const float*)d_in[0];
  const int* y = (const int*)d_in[1];
  float* out = (float*)d_out;
  char* ws = (char*)d_ws;

  float* xn = (float*)(ws);                     // 4 MB fp32 normalized
  _Float16* xnh = (_Float16*)(ws + (4 << 20));  // 2 MB f16 normalized
  float* partial = (float*)(ws + (6 << 20));    // 2 MB [8192][64]
  float* pS = (float*)(ws + (6 << 20));         // 1.31 MB, aliases partial
  float* S = (float*)(ws + (8 << 20));          // 5 KB class sums
  int* hist = (int*)(ws + (8 << 20) + 8192);    // 40 B class histogram

  hipMemsetAsync(hist, 0, 64, stream);
  hipMemsetAsync(out, 0, sizeof(float), stream);

  normalize_kernel<<<NROW / 4, 256, 0, stream>>>(x, xn, xnh);
  hist_kernel<<<16, 256, 0, stream>>>(y, hist);
  csum1_kernel<<<256, 256, 0, stream>>>(xn, y, pS);
  csum2_kernel<<<320, 256, 0, stream>>>(pS, S);
  gemm_exp_kernel<<<dim3(64, 64), 256, 0, stream>>>(xnh, partial);
  final_kernel<<<128, 256, 0, stream>>>(xn, y, S, hist, partial, out);
}

// Round 4
// 124.321 us; speedup vs baseline: 1.7538x; 1.0694x over previous
//
#include <hip/hip_runtime.h>
#include <hip/hip_bf16.h>

#define NROW 8192
#define CDIM 128
#define NCLS 10
#define NTILE 64           // 8192/128
#define NTRI 2080          // 64*65/2 upper-triangular tiles
// 1/(T*ln2) = 10*log2(e)
#define EXP2_SCALE 14.4269504088896f

typedef _Float16 f16x8 __attribute__((ext_vector_type(8)));
typedef _Float16 f16x2 __attribute__((ext_vector_type(2)));
typedef float f32x4 __attribute__((ext_vector_type(4)));

typedef __attribute__((address_space(1))) const unsigned int gu32;
typedef __attribute__((address_space(3))) unsigned int lu32;

__device__ __forceinline__ void gload_lds16(const _Float16* g, _Float16* l) {
  __builtin_amdgcn_global_load_lds((gu32*)g, (lu32*)l, 16, 0, 0);
}

// ---------------- normalize: x -> xn (f32), xnh (f16) -------------------
__global__ void normalize_kernel(const float* __restrict__ x,
                                 float* __restrict__ xn,
                                 _Float16* __restrict__ xnh) {
  const int w = threadIdx.x >> 6, l = threadIdx.x & 63;
  const int row = blockIdx.x * 4 + w;
  const float2 v = *(const float2*)&x[row * CDIM + l * 2];
  float ss = v.x * v.x + v.y * v.y;
#pragma unroll
  for (int off = 32; off; off >>= 1) ss += __shfl_xor(ss, off);
  const float nrm = fmaxf(sqrtf(ss), 1e-12f);
  const float a = v.x / nrm, b = v.y / nrm;
  ((float2*)xn)[row * 64 + l] = make_float2(a, b);
  f16x2 h;
  h[0] = (_Float16)a;
  h[1] = (_Float16)b;
  ((f16x2*)xnh)[row * 64 + l] = h;
}

// ------- per-class sums stage 1 (+ fused histogram), 256 blocks ---------
// pS layout TRANSPOSED: pS[i*256 + block] so stage 2 reads coalesce.
__global__ __launch_bounds__(256) void csum1_kernel(
    const float* __restrict__ xn, const int* __restrict__ y,
    float* __restrict__ pS, int* __restrict__ hist) {
  __shared__ float s[2][NCLS][CDIM];
  __shared__ int hcnt[NCLS];
  const int t = threadIdx.x;
  const int f = t & 127, h = t >> 7;
  for (int i = t; i < 2 * NCLS * CDIM; i += 256) ((float*)s)[i] = 0.f;
  if (t < NCLS) hcnt[t] = 0;
  __syncthreads();
  const int row0 = blockIdx.x * 32 + h * 16;
  float v[16];
  int c[16];
#pragma unroll
  for (int r = 0; r < 16; ++r) {
    v[r] = xn[(row0 + r) * CDIM + f];
    c[r] = y[row0 + r];
  }
#pragma unroll
  for (int r = 0; r < 16; ++r) s[h][c[r]][f] += v[r];
  if (f == 0) {
#pragma unroll
    for (int r = 0; r < 16; ++r) atomicAdd(&hcnt[c[r]], 1);
  }
  __syncthreads();
  for (int i = t; i < NCLS * CDIM; i += 256)
    pS[i * 256 + blockIdx.x] = ((float*)s[0])[i] + ((float*)s[1])[i];
  if (t < NCLS) atomicAdd(&hist[t], hcnt[t]);
}

// ------- per-class sums stage 2: one wave per (c,f), coalesced ----------
__global__ void csum2_kernel(const float* __restrict__ pS,
                             float* __restrict__ S) {
  const int w = threadIdx.x >> 6, l = threadIdx.x & 63;
  const int i = blockIdx.x * 4 + w;  // 0..1279
  const float4 v = *(const float4*)&pS[i * 256 + l * 4];
  float a = v.x + v.y + v.z + v.w;
#pragma unroll
  for (int off = 32; off; off >>= 1) a += __shfl_xor(a, off);
  if (l == 0) S[i] = a;
}

// ---------------- Gram GEMM + exp + row-sum epilogue --------------------
// Linearized upper-triangular grid (2080 blocks, balanced). 8 waves
// (512 thr), wave tile 64x32 (4x2 frags 16x16x32). Off-diagonal tiles emit
// both row-sums (bi rows, slot bj) and col-sums (bj rows, slot bi).
// LDS 16B chunks XOR-swizzled via pre-swizzled GLOBAL source (linear dest
// for global_load_lds); read side applies the same involution.
__global__ __launch_bounds__(512, 4) void gemm_exp_kernel(
    const _Float16* __restrict__ xnh, float* __restrict__ partial) {
  __shared__ _Float16 As[128 * 128];
  __shared__ _Float16 Bs[128 * 128];
  __shared__ float row_lds[128];
  __shared__ float col_lds[128];

  // decode linear triangular index -> (bi, bj), bj >= bi
  const int m = (NTRI - 1) - blockIdx.x;
  int r = (int)((sqrtf(8.f * (float)m + 1.f) - 1.f) * 0.5f);
  while ((r + 1) * (r + 2) / 2 <= m) ++r;
  while (r * (r + 1) / 2 > m) --r;
  const int k = m - r * (r + 1) / 2;
  const int bi = (NTILE - 1) - r, bj = (NTILE - 1) - k;
  const bool diag = (bi == bj);

  const int tid = threadIdx.x;
  const int l = tid & 63, w = tid >> 6;
  const int lane16 = l & 15, lanehi = l >> 4;

  if (tid < 128) {
    row_lds[tid] = 0.f;
    col_lds[tid] = 0.f;
  }

  // staging: waves 0-3 -> As, waves 4-7 -> Bs; 8 x 1KB chunks per wave
  {
    const int half = w >> 2;  // 0 = A, 1 = B
    const _Float16* srcb = xnh + (long)(half ? bj : bi) * 128 * CDIM;
    _Float16* dstb = half ? Bs : As;
#pragma unroll
    for (int i = 0; i < 8; ++i) {
      const int rg = ((w & 3) * 8 + i) * 4;  // first row of 1KB chunk
      const int rl = rg + lanehi;            // row this lane fetches
      const int csrc = lane16 ^ (rl & 7);    // pre-swizzled source chunk
      gload_lds16(&srcb[rl * CDIM + csrc * 8], &dstb[rg * 128]);
    }
  }
  __syncthreads();

  const int wr = w >> 2, wc = w & 3;  // 2 x 4 wave grid
  f32x4 acc[4][2];
#pragma unroll
  for (int fm = 0; fm < 4; ++fm)
#pragma unroll
    for (int fn = 0; fn < 2; ++fn) acc[fm][fn] = (f32x4){0.f, 0.f, 0.f, 0.f};

#pragma unroll
  for (int kk = 0; kk < 4; ++kk) {
    f16x8 a[4], b[2];
#pragma unroll
    for (int f = 0; f < 4; ++f) {
      const int ra = wr * 64 + f * 16 + lane16;
      const int ca = (kk * 4 + lanehi) ^ (ra & 7);
      a[f] = *(const f16x8*)&As[ra * 128 + ca * 8];
    }
#pragma unroll
    for (int f = 0; f < 2; ++f) {
      const int rb = wc * 32 + f * 16 + lane16;
      const int cb = (kk * 4 + lanehi) ^ (rb & 7);
      b[f] = *(const f16x8*)&Bs[rb * 128 + cb * 8];
    }
#pragma unroll
    for (int fm = 0; fm < 4; ++fm)
#pragma unroll
      for (int fn = 0; fn < 2; ++fn)
        acc[fm][fn] = __builtin_amdgcn_mfma_f32_16x16x32_f16(
            a[fm], b[fn], acc[fm][fn], 0, 0, 0);
  }

  // epilogue: exp2(s*scale); row partials pr[fm][e]; col sums per fn.
  const int growb = bi * 128 + wr * 64;
  const int gcolb = bj * 128 + wc * 32;
  float pr[4][4];
#pragma unroll
  for (int fm = 0; fm < 4; ++fm)
#pragma unroll
    for (int e = 0; e < 4; ++e) pr[fm][e] = 0.f;

#pragma unroll
  for (int fn = 0; fn < 2; ++fn) {
    float q = 0.f;
    const int col = gcolb + fn * 16 + lane16;
#pragma unroll
    for (int fm = 0; fm < 4; ++fm) {
#pragma unroll
      for (int e = 0; e < 4; ++e) {
        float v = exp2f(acc[fm][fn][e] * EXP2_SCALE);
        const int row = growb + fm * 16 + lanehi * 4 + e;
        if (diag && row == col) v = 0.f;
        pr[fm][e] += v;
        q += v;
      }
    }
    if (!diag) {
      q += __shfl_xor(q, 16);
      q += __shfl_xor(q, 32);
      if (l < 16) atomicAdd(&col_lds[wc * 32 + fn * 16 + l], q);
    }
  }
#pragma unroll
  for (int fm = 0; fm < 4; ++fm)
#pragma unroll
    for (int e = 0; e < 4; ++e) {
      float p = pr[fm][e];
      p += __shfl_xor(p, 1);
      p += __shfl_xor(p, 2);
      p += __shfl_xor(p, 4);
      p += __shfl_xor(p, 8);
      if (lane16 == 0)
        atomicAdd(&row_lds[wr * 64 + fm * 16 + lanehi * 4 + e], p);
    }
  __syncthreads();
  if (tid < 128) {
    partial[(long)(bi * 128 + tid) * 64 + bj] = row_lds[tid];
    if (!diag) partial[(long)(bj * 128 + tid) * 64 + bi] = col_lds[tid];
  }
}

// ---------------- final per-row loss + global reduce --------------------
__global__ void final_kernel(const float* __restrict__ xn,
                             const int* __restrict__ y,
                             const float* __restrict__ S,
                             const int* __restrict__ hist,
                             const float* __restrict__ partial,
                             float* __restrict__ out) {
  const int l = threadIdx.x & 63, w = threadIdx.x >> 6;
  const int waveid = blockIdx.x * 4 + w;  // 0..2047
  float accum = 0.f;
  for (int t = 0; t < 4; ++t) {
    const int row = waveid + 2048 * t;
    float d = partial[(long)row * 64 + l];  // coalesced col-block sums
    const int c = y[row];
    const float2 xv = *(const float2*)&xn[row * CDIM + l * 2];
    const float2 sv = *(const float2*)&S[c * CDIM + l * 2];
    float dot = xv.x * sv.x + xv.y * sv.y;
    float sf = xv.x * xv.x + xv.y * xv.y;
#pragma unroll
    for (int off = 32; off; off >>= 1) {
      d += __shfl_xor(d, off);
      dot += __shfl_xor(dot, off);
      sf += __shfl_xor(sf, off);
    }
    const int cnt = hist[c] - 1;
    float row_val = 0.f;
    if (cnt > 0) {
      const float possum = dot - sf;  // exclude self term
      row_val = -(possum * 10.0f - (float)cnt * logf(d)) / (float)cnt;
    }
    accum += row_val;
  }
  __shared__ float bsum[4];
  if (l == 0) bsum[w] = accum;
  __syncthreads();
  if (threadIdx.x == 0)
    atomicAdd(out, bsum[0] + bsum[1] + bsum[2] + bsum[3]);
}

extern "C" void kernel_launch(void* const* d_in, const int* in_sizes, int n_in,
                              void* d_out, int out_size, void* d_ws,
                              size_t ws_size, hipStream_t stream) {
  const float* x = (const float*)d_in[0];
  const int* y = (const int*)d_in[1];
  float* out = (float*)d_out;
  char* ws = (char*)d_ws;

  float* xn = (float*)(ws);                     // 4 MB fp32 normalized
  _Float16* xnh = (_Float16*)(ws + (4 << 20));  // 2 MB f16 normalized
  float* partial = (float*)(ws + (6 << 20));    // 2 MB [8192][64]
  float* pS = (float*)(ws + (6 << 20));         // 1.31 MB, aliases partial
  float* S = (float*)(ws + (8 << 20));          // 5 KB class sums
  int* hist = (int*)(ws + (8 << 20) + 8192);    // 40 B class histogram

  hipMemsetAsync(hist, 0, 64, stream);
  hipMemsetAsync(out, 0, sizeof(float), stream);

  normalize_kernel<<<NROW / 4, 256, 0, stream>>>(x, xn, xnh);
  csum1_kernel<<<256, 256, 0, stream>>>(xn, y, pS, hist);
  csum2_kernel<<<320, 256, 0, stream>>>(pS, S);
  gemm_exp_kernel<<<NTRI, 512, 0, stream>>>(xnh, partial);
  final_kernel<<<512, 256, 0, stream>>>(xn, y, S, hist, partial, out);
}